// Round 1
// 252.602 us; speedup vs baseline: 1.0470x; 1.0470x over previous
//
#include <hip/hip_runtime.h>

typedef unsigned short u16;
typedef unsigned int u32;
typedef __attribute__((ext_vector_type(8))) __bf16 bf16x8;
typedef __attribute__((ext_vector_type(4))) float floatx4;
typedef const __attribute__((address_space(1))) unsigned char glob_u8;
typedef __attribute__((address_space(3))) unsigned char lds_u8;

#define DEV __device__ __forceinline__

DEV u16 f2bf(float f) {
  u32 u = __builtin_bit_cast(u32, f);
  u = (u + 0x7fffu + ((u >> 16) & 1u)) >> 16;
  return (u16)u;
}
DEV float bf2f(u16 h) {
  u32 u = ((u32)h) << 16;
  return __builtin_bit_cast(float, u);
}
DEV floatx4 MFMA(bf16x8 a, bf16x8 b, floatx4 c) {
  return __builtin_amdgcn_mfma_f32_16x16x32_bf16(a, b, c, 0, 0, 0);
}

// ---------------- convert: x -> bf16, weights -> bf16 transposed -------------
__global__ void convert_k(const float* __restrict__ x, const float* __restrict__ Wq,
                          const float* __restrict__ Wkv, const float* __restrict__ Wg,
                          const float* __restrict__ Wo,
                          u16* __restrict__ xb, u16* __restrict__ WcatT, u16* __restrict__ WoT) {
  int i = blockIdx.x * 256 + threadIdx.x;
  if (i < 1048576) { xb[i] = f2bf(x[i]); return; }
  i -= 1048576;
  if (i < 524288) {
    int n = i >> 8, kk = i & 255;
    float v;
    if (n < 512) v = Wq[kk * 512 + n];
    else if (n < 1536) v = Wkv[kk * 1024 + (n - 512)];
    else v = Wg[kk * 512 + (n - 1536)];
    WcatT[i] = f2bf(v);
    return;
  }
  i -= 524288;
  if (i < 131072) {
    int n = i >> 9, kk = i & 511;
    WoT[i] = f2bf(Wo[kk * 256 + n]);
  }
}

// -------- GEMM1: 128x64 tiles; K/V written in MFMA-fragment order ------------
// kfrag[bh][t16][lane][8]: lane=(quad,l15) holds K[key=t*16+l15][d=half*32+quad*8+e]
//   (half selects the 512-u16 sub-block)
// vfrag[bh][t64][dt][ck][lane][8]: lane holds V[key=t*64+ck*32+quad*8+e][d=dt*16+l15]
__global__ __launch_bounds__(256, 4) void gemm_qkvg(
    const u16* __restrict__ xb, const u16* __restrict__ WcatT, const float* __restrict__ bg,
    u16* __restrict__ qb, u16* __restrict__ kfrag, u16* __restrict__ vfrag, u16* __restrict__ gb) {
  __shared__ __attribute__((aligned(16))) u16 As[128 * 40];
  __shared__ __attribute__((aligned(16))) u16 Bs[64 * 40];
  const int tid = threadIdx.x;
  const int wave = tid >> 6, lane = tid & 63;
  const int lane15 = lane & 15, quad = lane >> 4;
  const int rm0 = blockIdx.x * 128;
  const int cn0 = blockIdx.y * 64;
  const int wm = (wave & 1) * 64, wn = (wave >> 1) * 32;
  const int rowA = tid >> 1, segA = (tid & 1) * 16;
  const int rowB = tid >> 2, segB = (tid & 3) * 8;
  floatx4 acc[4][2] = {};
  uint4 a0 = *(const uint4*)(xb + (rm0 + rowA) * 256 + segA);
  uint4 a1 = *(const uint4*)(xb + (rm0 + rowA) * 256 + segA + 8);
  uint4 b0 = *(const uint4*)(WcatT + (cn0 + rowB) * 256 + segB);
#pragma unroll 1
  for (int k0 = 0; k0 < 256; k0 += 32) {
    __syncthreads();
    *(uint4*)(As + rowA * 40 + segA) = a0;
    *(uint4*)(As + rowA * 40 + segA + 8) = a1;
    *(uint4*)(Bs + rowB * 40 + segB) = b0;
    __syncthreads();
    if (k0 < 224) {
      a0 = *(const uint4*)(xb + (rm0 + rowA) * 256 + k0 + 32 + segA);
      a1 = *(const uint4*)(xb + (rm0 + rowA) * 256 + k0 + 32 + segA + 8);
      b0 = *(const uint4*)(WcatT + (cn0 + rowB) * 256 + k0 + 32 + segB);
    }
    bf16x8 af[4], bfr[2];
#pragma unroll
    for (int mt = 0; mt < 4; ++mt) af[mt] = *(const bf16x8*)(As + (wm + mt * 16 + lane15) * 40 + quad * 8);
#pragma unroll
    for (int nt = 0; nt < 2; ++nt) bfr[nt] = *(const bf16x8*)(Bs + (wn + nt * 16 + lane15) * 40 + quad * 8);
#pragma unroll
    for (int mt = 0; mt < 4; ++mt)
#pragma unroll
      for (int nt = 0; nt < 2; ++nt)
        acc[mt][nt] = MFMA(af[mt], bfr[nt], acc[mt][nt]);
  }
#pragma unroll
  for (int mt = 0; mt < 4; ++mt)
#pragma unroll
    for (int nt = 0; nt < 2; ++nt)
#pragma unroll
      for (int r = 0; r < 4; ++r) {
        int row = rm0 + wm + mt * 16 + quad * 4 + r;
        int col = cn0 + wn + nt * 16 + lane15;
        float v = acc[mt][nt][r];
        int b = row >> 10, n = row & 1023;
        if (col < 512) {
          int h = col >> 6, d = col & 63;
          qb[((b * 8 + h) * 1024 + n) * 64 + d] = f2bf(v * 0.125f);
        } else if (col < 1024) {
          int c = col - 512, h = c >> 6, d = c & 63;
          int bh2 = b * 8 + h;
          int t = n >> 4, l15 = n & 15;
          int half = d >> 5, qd = (d >> 3) & 3, e = d & 7;
          kfrag[(size_t)bh2 * 65536 + t * 1024 + half * 512 + (qd * 16 + l15) * 8 + e] = f2bf(v);
        } else if (col < 1536) {
          int c = col - 1024, h = c >> 6, d = c & 63;
          int bh2 = b * 8 + h;
          int t64 = n >> 6, ck = (n >> 5) & 1, qd = (n >> 3) & 3, e = n & 7;
          int dt = d >> 4, l15 = d & 15;
          vfrag[(size_t)bh2 * 65536 + t64 * 4096 + dt * 1024 + ck * 512 + (qd * 16 + l15) * 8 + e] = f2bf(v);
        } else {
          int c = col - 1536;
          float g = 1.0f / (1.0f + __expf(-(v + bg[c])));
          gb[row * 512 + c] = f2bf(g);
        }
      }
}

// ------- fused attention: full-K (1024 keys), double-buffered DMA pipeline ---
// grid (32,16)=512 blocks; LDS ~74 KB -> 2 blocks/CU (fully resident).
// 2-phase: issue tile t+1's global_load_lds, compute tile t, one barrier/tile
// (its implicit vmcnt(0) drains the prefetch). Normalization + gate fused into
// the epilogue -> writes ogb bf16 directly (no po/pl partials, no merge pass).
__global__ __launch_bounds__(256, 2) void attn_k(
    const u16* __restrict__ qb, const u16* __restrict__ kfrag, const u16* __restrict__ vfrag,
    const float* __restrict__ bias, const u16* __restrict__ gb, u16* __restrict__ ogb) {
  __shared__ __attribute__((aligned(16))) u16 Kt[2][4096];    // 2 x 8 KB frag-order keys
  __shared__ __attribute__((aligned(16))) u16 Vt[2][4096];    // 2 x 8 KB frag-order values
  __shared__ __attribute__((aligned(16))) float Bt[2][4096];  // 2 x 16 KB bias 64q x 64k
  __shared__ __attribute__((aligned(16))) u16 Ps[4 * 16 * 72];
  const int tid = threadIdx.x;
  const int wave = tid >> 6, lane = tid & 63;
  const int lane15 = lane & 15, quad = lane >> 4;
  const int bh = blockIdx.x;
  const int q0 = blockIdx.y * 64;

  bf16x8 qf0, qf1;
  {
    const u16* qrow = qb + ((size_t)(bh * 1024 + q0 + wave * 16 + lane15)) * 64 + quad * 8;
    qf0 = *(const bf16x8*)(qrow);
    qf1 = *(const bf16x8*)(qrow + 32);
  }
  bf16x8 ones;
#pragma unroll
  for (int e = 0; e < 8; ++e) ones[e] = __builtin_bit_cast(__bf16, (u16)0x3F80);

  floatx4 oacc[4] = {};
  floatx4 lacc = {};

  u16* Pw = Ps + wave * (16 * 72);
  const u16* kp = kfrag + (size_t)bh * 65536;
  const u16* vp = vfrag + (size_t)bh * 65536;

  // ---- DMA stage of one 64-key tile into buffer bufi (8 loads/wave) ----
  auto stage = [&](int kt, int bufi) {
    const int kb0 = kt * 64;
    const u16* kS = kp + kb0 * 64;
    const u16* vS = vp + kb0 * 64;
#pragma unroll
    for (int c = 0; c < 2; ++c) {
      int ch = wave * 2 + c;
      __builtin_amdgcn_global_load_lds((glob_u8*)(kS + ch * 512 + lane * 8),
                                       (lds_u8*)(&Kt[bufi][ch * 512]), 16, 0, 0);
      __builtin_amdgcn_global_load_lds((glob_u8*)(vS + ch * 512 + lane * 8),
                                       (lds_u8*)(&Vt[bufi][ch * 512]), 16, 0, 0);
    }
#pragma unroll
    for (int c = 0; c < 4; ++c) {
      int ch = wave * 4 + c;
      const float* bS = bias + ((size_t)(bh * 1024 + q0 + ch * 4 + quad)) * 1024 + kb0 + lane15 * 4;
      __builtin_amdgcn_global_load_lds((glob_u8*)bS, (lds_u8*)(&Bt[bufi][ch * 256]), 16, 0, 0);
    }
  };

  stage(0, 0);
  __syncthreads();   // implicit vmcnt(0): tile 0 resident
  int cur = 0;
#pragma unroll 1
  for (int kt = 0; kt < 16; ++kt) {
    if (kt < 15) stage(kt + 1, cur ^ 1);   // prefetch overlaps compute below
    const u16* Ktc = Kt[cur];
    const u16* Vtc = Vt[cur];
    const float* Btc = Bt[cur];
    // ---- S = Q K^T  (conflict-free lane*16 ds_read_b128) ----
    floatx4 s[4];
#pragma unroll
    for (int j = 0; j < 4; ++j) {
      bf16x8 kf0 = *(const bf16x8*)(Ktc + j * 1024 + lane * 8);
      bf16x8 kf1 = *(const bf16x8*)(Ktc + j * 1024 + 512 + lane * 8);
      floatx4 z = {};
      z = MFMA(qf0, kf0, z);
      s[j] = MFMA(qf1, kf1, z);
    }
    // ---- fixed-max softmax: p = exp(s + bias - 8) ----
#pragma unroll
    for (int j = 0; j < 4; ++j)
#pragma unroll
      for (int r = 0; r < 4; ++r)
        s[j][r] = __expf(s[j][r] + Btc[(wave * 16 + quad * 4 + r) * 64 + j * 16 + lane15] - 8.0f);
    // ---- P -> wave-private LDS (C-layout write, A-layout read) ----
#pragma unroll
    for (int j = 0; j < 4; ++j)
#pragma unroll
      for (int r = 0; r < 4; ++r)
        Pw[(quad * 4 + r) * 72 + j * 16 + lane15] = f2bf(s[j][r]);
    bf16x8 pf0 = *(const bf16x8*)(Pw + lane15 * 72 + quad * 8);
    bf16x8 pf1 = *(const bf16x8*)(Pw + lane15 * 72 + 32 + quad * 8);

    // ---- l += P·1 ; O += P·V ----
    lacc = MFMA(pf0, ones, lacc);
    lacc = MFMA(pf1, ones, lacc);
#pragma unroll
    for (int dt = 0; dt < 4; ++dt) {
      bf16x8 vf0 = *(const bf16x8*)(Vtc + dt * 1024 + lane * 8);
      bf16x8 vf1 = *(const bf16x8*)(Vtc + dt * 1024 + 512 + lane * 8);
      oacc[dt] = MFMA(pf0, vf0, oacc[dt]);
      oacc[dt] = MFMA(pf1, vf1, oacc[dt]);
    }
    __syncthreads();   // drains prefetch (vmcnt(0)) + protects buf[cur] reuse
    cur ^= 1;
  }

  // ---- fused epilogue: normalize by l, apply gate, write ogb bf16 ----
  const int b = bh >> 3, h = bh & 7;
#pragma unroll
  for (int r = 0; r < 4; ++r) {
    int q = q0 + wave * 16 + quad * 4 + r;
    float inv = 1.0f / lacc[r];
    size_t base = ((size_t)(b * 1024 + q)) * 512 + h * 64;
#pragma unroll
    for (int dt = 0; dt < 4; ++dt) {
      size_t gi = base + dt * 16 + lane15;
      ogb[gi] = f2bf(oacc[dt][r] * inv * bf2f(gb[gi]));
    }
  }
}

// ------- GEMM2: 64x64 tiles, full K=512, fused +bo, fp32 out -----------------
__global__ __launch_bounds__(256, 4) void gemm_out_k(
    const u16* __restrict__ og, const u16* __restrict__ WoT,
    const float* __restrict__ bo, float* __restrict__ out) {
  __shared__ __attribute__((aligned(16))) u16 As[64 * 40];
  __shared__ __attribute__((aligned(16))) u16 Bs[64 * 40];
  const int tid = threadIdx.x;
  const int wave = tid >> 6, lane = tid & 63;
  const int lane15 = lane & 15, quad = lane >> 4;
  const int rm0 = blockIdx.x * 64;
  const int cn0 = blockIdx.y * 64;
  const int wm = (wave & 1) * 32, wn = (wave >> 1) * 32;
  const int rowA = tid >> 2, segA = (tid & 3) * 8;
  floatx4 acc[2][2] = {};
  uint4 a0 = *(const uint4*)(og + (rm0 + rowA) * 512 + segA);
  uint4 b0 = *(const uint4*)(WoT + (cn0 + rowA) * 512 + segA);
#pragma unroll 1
  for (int k0 = 0; k0 < 512; k0 += 32) {
    __syncthreads();
    *(uint4*)(As + rowA * 40 + segA) = a0;
    *(uint4*)(Bs + rowA * 40 + segA) = b0;
    __syncthreads();
    if (k0 < 480) {
      a0 = *(const uint4*)(og + (rm0 + rowA) * 512 + k0 + 32 + segA);
      b0 = *(const uint4*)(WoT + (cn0 + rowA) * 512 + k0 + 32 + segA);
    }
    bf16x8 af[2], bfr[2];
#pragma unroll
    for (int mt = 0; mt < 2; ++mt) af[mt] = *(const bf16x8*)(As + (wm + mt * 16 + lane15) * 40 + quad * 8);
#pragma unroll
    for (int nt = 0; nt < 2; ++nt) bfr[nt] = *(const bf16x8*)(Bs + (wn + nt * 16 + lane15) * 40 + quad * 8);
#pragma unroll
    for (int mt = 0; mt < 2; ++mt)
#pragma unroll
      for (int nt = 0; nt < 2; ++nt)
        acc[mt][nt] = MFMA(af[mt], bfr[nt], acc[mt][nt]);
  }
#pragma unroll
  for (int nt = 0; nt < 2; ++nt) {
    int col = cn0 + wn + nt * 16 + lane15;
    float bv = bo[col];
#pragma unroll
    for (int mt = 0; mt < 2; ++mt)
#pragma unroll
      for (int r = 0; r < 4; ++r) {
        int row = rm0 + wm + mt * 16 + quad * 4 + r;
        out[(size_t)row * 256 + col] = acc[mt][nt][r] + bv;
      }
  }
}

extern "C" void kernel_launch(void* const* d_in, const int* in_sizes, int n_in,
                              void* d_out, int out_size, void* d_ws, size_t ws_size,
                              hipStream_t stream) {
  const float* x = (const float*)d_in[0];
  const float* bias = (const float*)d_in[1];
  const float* Wq = (const float*)d_in[2];
  const float* Wkv = (const float*)d_in[3];
  const float* Wo = (const float*)d_in[4];
  const float* bo = (const float*)d_in[5];
  const float* Wg = (const float*)d_in[6];
  const float* bg = (const float*)d_in[7];
  float* out = (float*)d_out;
  char* ws = (char*)d_ws;
  u16* xb    = (u16*)(ws);                 // 2 MB
  u16* WcatT = (u16*)(ws + 2097152);       // 1 MB
  u16* WoT   = (u16*)(ws + 3145728);       // 256 KB
  u16* qb    = (u16*)(ws + 3407872);       // 4 MB
  u16* kfrag = (u16*)(ws + 7602176);       // 4 MB
  u16* vfrag = (u16*)(ws + 11796480);      // 4 MB
  u16* gb    = (u16*)(ws + 15990784);      // 4 MB
  u16* ogb   = (u16*)(ws + 20185088);      // 4 MB

  convert_k<<<6656, 256, 0, stream>>>(x, Wq, Wkv, Wg, Wo, xb, WcatT, WoT);
  dim3 g1(32, 32);
  gemm_qkvg<<<g1, 256, 0, stream>>>(xb, WcatT, bg, qb, kfrag, vfrag, gb);
  dim3 g2(32, 16);
  attn_k<<<g2, 256, 0, stream>>>(qb, kfrag, vfrag, bias, gb, ogb);
  dim3 g3(64, 4);
  gemm_out_k<<<g3, 256, 0, stream>>>(ogb, WoT, bo, out);
}